// Round 2
// baseline (2269.705 us; speedup 1.0000x reference)
//
#include <hip/hip_runtime.h>

// Problem constants (match reference)
constexpr int NB   = 8;     // batches
constexpr int NC   = 64;    // channels
constexpr int NN   = 8192;  // points
constexpr int NM   = 2048;  // samples
constexpr int NK   = 16;    // knn
constexpr int NFPS = 1433;  // int(2048*0.7)
constexpr int NRAND = NM - NFPS; // 615

// ---------------- workspace layout (bytes) ----------------
constexpr size_t OFF_START = 0;
constexpr size_t OFF_SUB1  = 64;
constexpr size_t OFF_SUB2  = 128;
constexpr size_t OFF_IDX   = 256;      // int idx[8][2048]
constexpr size_t OFF_V1    = 66048;    // uint v1[8][8192]
constexpr size_t OFF_KNN   = 328448;   // int knn[8][2048][16]
constexpr size_t OFF_XT    = 1377280;  // float xT[8][8192][64]

struct TF { unsigned a, b; };

__device__ __forceinline__ TF tf2(unsigned k0, unsigned k1, unsigned c0, unsigned c1) {
  unsigned ks2 = k0 ^ k1 ^ 0x1BD11BDAu;
  unsigned x0 = c0 + k0;
  unsigned x1 = c1 + k1;
#define TF_R(r) { x0 += x1; x1 = (x1 << r) | (x1 >> (32 - r)); x1 ^= x0; }
  TF_R(13) TF_R(15) TF_R(26) TF_R(6)
  x0 += k1;  x1 += ks2 + 1u;
  TF_R(17) TF_R(29) TF_R(16) TF_R(24)
  x0 += ks2; x1 += k0 + 2u;
  TF_R(13) TF_R(15) TF_R(26) TF_R(6)
  x0 += k0;  x1 += k1 + 3u;
  TF_R(17) TF_R(29) TF_R(16) TF_R(24)
  x0 += k1;  x1 += ks2 + 4u;
  TF_R(13) TF_R(15) TF_R(26) TF_R(6)
  x0 += ks2; x1 += k0 + 5u;
#undef TF_R
  TF r; r.a = x0; r.b = x1; return r;
}

// ---------------- PRNG setup (jax_threefry_partitionable=True, verified R1) ----------------
__global__ void rng_setup(unsigned* __restrict__ startB,
                          unsigned* __restrict__ sub1,
                          unsigned* __restrict__ sub2) {
  if (threadIdx.x != 0) return;
  const unsigned K0 = 0u, K1 = 42u; // jax.random.key(42)
  for (int b = 0; b < NB; ++b) {
    TF kb = tf2(K0, K1, 0u, (unsigned)b);
    TF k2 = tf2(kb.a, kb.b, 0u, 1u);
    TF bt = tf2(k2.a, k2.b, 0u, 0u);
    startB[b] = (bt.a ^ bt.b) & (unsigned)(NN - 1);
  }
  TF keyr = tf2(K0, K1, 0u, 1u); // fold_in(key42, 1)
  for (int b = 0; b < NB; ++b) {
    TF rk = tf2(keyr.a, keyr.b, 0u, (unsigned)b);   // rkeys[b]
    TF s1 = tf2(rk.a, rk.b, 0u, 1u);                // round-1 subkey
    TF nk = tf2(rk.a, rk.b, 0u, 0u);                // round-1 carried key
    TF s2 = tf2(nk.a, nk.b, 0u, 1u);                // round-2 subkey
    sub1[2*b] = s1.a; sub1[2*b+1] = s1.b;
    sub2[2*b] = s2.a; sub2[2*b+1] = s2.b;
  }
}

// DPP-based wave64 max (VALU latency, no LDS on the chain).
// row_shr:1/2/4/8 build per-row(16) prefix max; row_bcast15 (rows 1,3) and
// row_bcast31 (rows 2,3) merge rows; lane 63 holds the full-wave max.
__device__ __forceinline__ float wave_max_dpp(float v) {
  int vi;
  vi = __builtin_amdgcn_update_dpp(__float_as_int(v), __float_as_int(v), 0x111, 0xf, 0xf, false);
  v = fmaxf(v, __int_as_float(vi));
  vi = __builtin_amdgcn_update_dpp(__float_as_int(v), __float_as_int(v), 0x112, 0xf, 0xf, false);
  v = fmaxf(v, __int_as_float(vi));
  vi = __builtin_amdgcn_update_dpp(__float_as_int(v), __float_as_int(v), 0x114, 0xf, 0xf, false);
  v = fmaxf(v, __int_as_float(vi));
  vi = __builtin_amdgcn_update_dpp(__float_as_int(v), __float_as_int(v), 0x118, 0xf, 0xf, false);
  v = fmaxf(v, __int_as_float(vi));
  vi = __builtin_amdgcn_update_dpp(__float_as_int(v), __float_as_int(v), 0x142, 0xa, 0xf, false);
  v = fmaxf(v, __int_as_float(vi));
  vi = __builtin_amdgcn_update_dpp(__float_as_int(v), __float_as_int(v), 0x143, 0xc, 0xf, false);
  v = fmaxf(v, __int_as_float(vi));
  return __int_as_float(__builtin_amdgcn_readlane(__float_as_int(v), 63));
}

// 4-step DPP row(16) prefix-max on a sortable u64 composite.
// After the chain, lane 15 of each 16-lane row holds max over its row.
__device__ __forceinline__ unsigned long long row_prefix_max16_u64(unsigned long long v) {
#define RP_STEP(ctrl) {                                                              \
    unsigned lo = (unsigned)v, hi = (unsigned)(v >> 32);                             \
    unsigned olo = (unsigned)__builtin_amdgcn_update_dpp((int)lo, (int)lo, ctrl, 0xf, 0xf, false); \
    unsigned ohi = (unsigned)__builtin_amdgcn_update_dpp((int)hi, (int)hi, ctrl, 0xf, 0xf, false); \
    unsigned long long o = ((unsigned long long)ohi << 32) | olo;                    \
    v = (o > v) ? o : v; }
  RP_STEP(0x111) RP_STEP(0x112) RP_STEP(0x114) RP_STEP(0x118)
#undef RP_STEP
  return v;
}

// ---------------- FPS: one block (1024 thr, 16 waves) per batch ----------------
// 1432 serial argmax steps. Per-CU VALU issue work is fixed (~770 cyc/iter);
// 4 waves/SIMD (vs 1 before) overlap the dependent-chain / DPP / LDS-latency
// stalls that previously doubled the iteration time. Per step: 8-slot register
// dist update (12 ops) -> DPP wave max + ballot/ctz/readlane arg -> 1-of-16
// LDS composite slot ((distbits<<32)|~idx, dist>=0 so float bits sort as uint,
// ~idx makes ties pick the smallest index) -> ONE barrier (parity
// double-buffer) -> broadcast read slot[lane&15] + 4-step DPP row prefix-max
// + readlane(15) -> uniform LDS coord fetch.
// Tie-break = first index exactly (lane order == index order; composite ~idx).
__global__ __launch_bounds__(1024, 4) void fps_kernel(const float* __restrict__ pos,
                                                      const unsigned* __restrict__ startB,
                                                      int* __restrict__ idx) {
  __shared__ float ldsX[NN];   // 32 KB
  __shared__ float ldsY[NN];   // 32 KB
  __shared__ float ldsZ[NN];   // 32 KB
  __shared__ unsigned long long slotU[2][16];
  const int b = blockIdx.x;
  const int tid = threadIdx.x;
  const int wv = tid >> 6, lane = tid & 63;
  const float* pb = pos + (size_t)b * 3 * NN;
  constexpr int SLOTS = NN / 1024;   // 8
  float px[SLOTS], py[SLOTS], pz[SLOTS], dist[SLOTS];
  const int base = tid * SLOTS;   // tid-major ownership => lane order == index order
  const float4* fx = (const float4*)(pb + base);
  const float4* fy = (const float4*)(pb + NN + base);
  const float4* fz = (const float4*)(pb + 2 * NN + base);
#pragma unroll
  for (int q = 0; q < SLOTS / 4; ++q) {
    float4 a = fx[q], c = fy[q], e = fz[q];
    px[4*q] = a.x; px[4*q+1] = a.y; px[4*q+2] = a.z; px[4*q+3] = a.w;
    py[4*q] = c.x; py[4*q+1] = c.y; py[4*q+2] = c.z; py[4*q+3] = c.w;
    pz[4*q] = e.x; pz[4*q+1] = e.y; pz[4*q+2] = e.z; pz[4*q+3] = e.w;
    ((float4*)(ldsX + base))[q] = a;   // one-time stage (conflicts OK, ~1 µs)
    ((float4*)(ldsY + base))[q] = c;
    ((float4*)(ldsZ + base))[q] = e;
  }
#pragma unroll
  for (int s = 0; s < SLOTS; ++s) dist[s] = 1e10f;
  int widx = (int)startB[b];
  if (tid == 0) idx[b * NM] = widx;
  __syncthreads();
  float cx = ldsX[widx], cy = ldsY[widx], cz = ldsZ[widx];
  for (int it = 1; it < NFPS; ++it) {
    const int par = it & 1;
    float bestv = -1.0f; int bestS = 0;
#pragma unroll
    for (int s = 0; s < SLOTS; ++s) {
      // Mirror numpy/XLA exactly: rn ops, no FMA contraction, ((dx2+dy2)+dz2)
      float dx = __fsub_rn(px[s], cx);
      float dy = __fsub_rn(py[s], cy);
      float dz = __fsub_rn(pz[s], cz);
      float d  = __fadd_rn(__fadd_rn(__fmul_rn(dx, dx), __fmul_rn(dy, dy)),
                           __fmul_rn(dz, dz));
      float nd = fminf(dist[s], d);
      dist[s] = nd;
      bool c = nd > bestv;            // strict > keeps first (smallest) index
      bestv = c ? nd : bestv;
      bestS = c ? s : bestS;
    }
    const int gidx = base + bestS;
    const float wm = wave_max_dpp(bestv);
    unsigned long long msk = __ballot(bestv == wm);  // nonzero: max lane matches
    const int fl = (int)__builtin_ctzll(msk);        // lowest lane = smallest index
    const int widxw = __builtin_amdgcn_readlane(gidx, fl);
    if (lane == 0)
      slotU[par][wv] = ((unsigned long long)__float_as_uint(wm) << 32)
                       | (unsigned)(~widxw);
    __syncthreads();
    // block merge: broadcast-read the 16 wave composites, DPP row prefix-max
    unsigned long long comp = slotU[par][lane & 15];
    comp = row_prefix_max16_u64(comp);
    const int lo15 = __builtin_amdgcn_readlane((int)(unsigned)comp, 15);
    widx = (int)(~(unsigned)lo15);
    cx = ldsX[widx]; cy = ldsY[widx]; cz = ldsZ[widx];  // uniform broadcast reads
    if (tid == 0) idx[b * NM + it] = widx;
  }
}

// ---------------- permutation: 2 independent stable sorts, 16 blocks ----------------
__device__ void bitonic8192(unsigned long long* s, int tid) {
  for (unsigned k = 2; k <= 8192u; k <<= 1) {
    for (unsigned j = k >> 1; j > 0; j >>= 1) {
      __syncthreads();
      for (unsigned t = (unsigned)tid; t < 4096u; t += 1024u) {
        unsigned i = ((t & ~(j - 1u)) << 1) | (t & (j - 1u));
        unsigned p = i | j;
        bool up = ((i & k) == 0u);
        unsigned long long a = s[i], c = s[p];
        if ((a > c) == up) { s[i] = c; s[p] = a; }
      }
    }
  }
  __syncthreads();
}

// block = (batch, round). Round 0 writes the full round-1 permutation v1;
// round 1 writes its first NRAND payload positions into idx (composed later).
__global__ __launch_bounds__(1024) void perm_kernel(const unsigned* __restrict__ sub1,
                                                    const unsigned* __restrict__ sub2,
                                                    unsigned* __restrict__ v1buf,
                                                    int* __restrict__ idx) {
  __shared__ unsigned long long s[NN]; // 64 KB
  const int bl = blockIdx.x;
  const int b = bl >> 1, r = bl & 1;
  const int tid = threadIdx.x;
  const unsigned* sk = (r == 0) ? sub1 : sub2;
  const unsigned ka = sk[2*b], kb = sk[2*b+1];
  for (int i = tid; i < NN; i += 1024) {
    TF t = tf2(ka, kb, 0u, (unsigned)i);
    // composite (key<<32)|position => stable sort incl. key collisions
    s[i] = ((unsigned long long)(t.a ^ t.b) << 32) | (unsigned)i;
  }
  bitonic8192(s, tid);
  if (r == 0) {
    unsigned* v1 = v1buf + (size_t)b * NN;
    for (int i = tid; i < NN; i += 1024) v1[i] = (unsigned)(s[i] & 0xffffffffu);
  } else {
    for (int t = tid; t < NRAND; t += 1024)
      idx[b * NM + NFPS + t] = (int)(s[t] & 0xffffffffu);
  }
}

// ---------------- pos_sub gather (composes v1[v2] for the random part) ----------------
__global__ void possub_kernel(const float* __restrict__ pos,
                              const int* __restrict__ idx,
                              const unsigned* __restrict__ v1,
                              float* __restrict__ posOut) {
  int i = blockIdx.x * 256 + threadIdx.x;
  if (i >= NB * 3 * NM) return;
  int mm = i & (NM - 1);
  int bd = i >> 11;            // b*3 + d
  int d = bd % 3, b = bd / 3;
  int raw = idx[b * NM + mm];
  int id = (mm < NFPS) ? raw : (int)v1[(size_t)b * NN + raw];
  posOut[i] = pos[((size_t)b * 3 + d) * NN + id];
}

// ---------------- transpose x [B,C,N] -> xT [B,N,C] ----------------
__global__ void transpose_kernel(const float* __restrict__ x, float* __restrict__ xT) {
  __shared__ float t[32][33];
  int b = blockIdx.z;
  int n0 = blockIdx.x * 32, c0 = blockIdx.y * 32;
  int tx = threadIdx.x, ty = threadIdx.y;
  t[ty][tx] = x[((size_t)b * NC + (c0 + ty)) * NN + n0 + tx];
  __syncthreads();
  xT[((size_t)b * NN + (n0 + ty)) * NC + c0 + tx] = t[tx][ty];
}

// ---------------- KNN: one wave per sampled point ----------------
// Per-lane top-16 in registers (branchless v_med3 chain); LDS only for the
// final 64-list wave merge (verified R3).
__global__ __launch_bounds__(256) void knn_kernel(const float* __restrict__ pos,
                                                  const float* __restrict__ posSub,
                                                  int* __restrict__ knn) {
  __shared__ unsigned long long lst[4][NK][64]; // [wave][rank][lane], 32 KB
  const int tid = threadIdx.x;
  const int wv = tid >> 6, lane = tid & 63;
  const int g = blockIdx.x * 4 + wv;            // 0..16383
  const int b = g >> 11, mm = g & (NM - 1);
  const float* pb = pos + (size_t)b * 3 * NN;
  const float* ps = posSub + (size_t)b * 3 * NM;
  const float sx = ps[mm], sy = ps[NM + mm], sz = ps[2 * NM + mm];
  const float sm = __fadd_rn(__fadd_rn(__fmul_rn(sx, sx), __fmul_rn(sy, sy)),
                             __fmul_rn(sz, sz));
  float key[NK]; int kid[NK];
#pragma unroll
  for (int i = 0; i < NK; ++i) { key[i] = __int_as_float(0x7F800000); kid[i] = 0; }
  for (int t = 0; t < NN / 64; ++t) {
    const int n = t * 64 + lane;
    float x = pb[n], y = pb[NN + n], z = pb[2 * NN + n];
    float sn = __fadd_rn(__fadd_rn(__fmul_rn(x, x), __fmul_rn(y, y)), __fmul_rn(z, z));
    float dt = __fadd_rn(__fadd_rn(__fmul_rn(sx, x), __fmul_rn(sy, y)), __fmul_rn(sz, z));
    float d2 = __fsub_rn(__fadd_rn(sm, sn), __fmul_rn(2.0f, dt)); // mirror reference
    const float ck = d2; const int ci = n;
    // branchless sorted insert, descending so olds are read before overwrite;
    // strict < => equal keys keep earlier (smaller-index) candidate first
#pragma unroll
    for (int i = NK - 1; i >= 1; --i) {
      float lo = key[i-1], hi = key[i];
      bool cLo = ck < lo, cHi = ck < hi;
      key[i] = __builtin_amdgcn_fmed3f(ck, lo, hi);
      kid[i] = cLo ? kid[i-1] : (cHi ? ci : kid[i]);
    }
    bool c0 = ck < key[0];
    kid[0] = c0 ? ci : kid[0];
    key[0] = fminf(key[0], ck);
  }
  // dump sorted lists (order-flipped keys) to LDS; same-wave access, no barrier
#pragma unroll
  for (int i = 0; i < NK; ++i) {
    unsigned u = __float_as_uint(key[i]);
    u = (u & 0x80000000u) ? ~u : (u | 0x80000000u);
    lst[wv][i][lane] = ((unsigned long long)u << 32) | (unsigned)kid[i];
  }
  // merge 64 sorted lists: 16 rounds of wave-min; unique composites => safe pop
  int ptr = 0;
  unsigned long long head = lst[wv][0][lane];
  unsigned myn = 0;
  for (int k = 0; k < NK; ++k) {
    unsigned long long mn = head;
#pragma unroll
    for (int off = 32; off > 0; off >>= 1) {
      unsigned long long o = __shfl_xor(mn, off, 64);
      if (o < mn) mn = o;
    }
    if (head == mn) { ++ptr; head = (ptr < NK) ? lst[wv][ptr][lane] : ~0ull; }
    if (lane == k) myn = (unsigned)(mn & 0xffffffffu);
  }
  if (lane < NK) knn[(size_t)g * NK + lane] = (int)myn;
}

// ---------------- weights + gather + weighted sum ----------------
__global__ __launch_bounds__(256) void final_kernel(const float* __restrict__ xT,
                                                    const float* __restrict__ pos,
                                                    const float* __restrict__ posSub,
                                                    const int* __restrict__ knn,
                                                    float* __restrict__ xOut) {
  __shared__ float tile[64][17];
  const int tid = threadIdx.x;
  const int wv = tid >> 6, lane = tid & 63;
  const int base = blockIdx.x * 16;      // 16 consecutive samples, same batch
  const int b = base >> 11;
  const float* pb = pos + (size_t)b * 3 * NN;
  const float* ps = posSub + (size_t)b * 3 * NM;
  for (int j = 0; j < 4; ++j) {
    const int ml = wv * 4 + j;           // 0..15
    const int g = base + ml;
    const int mm = g & (NM - 1);
    const float sx = ps[mm], sy = ps[NM + mm], sz = ps[2 * NM + mm];
    const int kk = lane & 15;
    const int nk = knn[(size_t)g * NK + kk];
    float dx = __fsub_rn(pb[nk], sx);
    float dy = __fsub_rn(pb[NN + nk], sy);
    float dz = __fsub_rn(pb[2 * NN + nk], sz);
    float dd = __fadd_rn(__fadd_rn(__fmul_rn(dx, dx), __fmul_rn(dy, dy)),
                         __fmul_rn(dz, dz));
    float d = __fsqrt_rn(dd);
    d = fmaxf(d, 1e-6f);
    float e = __fdiv_rn(0.0f - d, 0.2f);
    float mx = e;
#pragma unroll
    for (int off = 8; off > 0; off >>= 1) mx = fmaxf(mx, __shfl_xor(mx, off, 16));
    float ex = expf(__fsub_rn(e, mx));
    float sum = ex;
#pragma unroll
    for (int off = 8; off > 0; off >>= 1) sum = __fadd_rn(sum, __shfl_xor(sum, off, 16));
    float wgt = __fdiv_rn(ex, sum);
    float acc = 0.0f;
#pragma unroll
    for (int k = 0; k < NK; ++k) {
      float wk = __shfl(wgt, k, 64);
      int   nn = __shfl(nk, k, 64);
      acc = __fadd_rn(acc, __fmul_rn(wk, xT[((size_t)b * NN + nn) * NC + lane]));
    }
    tile[lane][ml] = acc;
  }
  __syncthreads();
  const int m0 = base & (NM - 1);
  for (int e2 = tid; e2 < 64 * 16; e2 += 256) {
    int c = e2 >> 4, ml = e2 & 15;
    xOut[((size_t)b * NC + c) * NM + m0 + ml] = tile[c][ml];
  }
}

extern "C" void kernel_launch(void* const* d_in, const int* in_sizes, int n_in,
                              void* d_out, int out_size, void* d_ws, size_t ws_size,
                              hipStream_t stream) {
  const float* x   = (const float*)d_in[0];
  const float* pos = (const float*)d_in[1];
  float* xOut   = (float*)d_out;
  float* posOut = xOut + (size_t)NB * NC * NM;

  char* w = (char*)d_ws;
  unsigned* startB = (unsigned*)(w + OFF_START);
  unsigned* sub1   = (unsigned*)(w + OFF_SUB1);
  unsigned* sub2   = (unsigned*)(w + OFF_SUB2);
  int*      idx    = (int*)(w + OFF_IDX);
  unsigned* v1     = (unsigned*)(w + OFF_V1);
  int*      knn    = (int*)(w + OFF_KNN);
  float*    xT     = (float*)(w + OFF_XT);

  hipLaunchKernelGGL(rng_setup, dim3(1), dim3(64), 0, stream, startB, sub1, sub2);
  hipLaunchKernelGGL(fps_kernel, dim3(NB), dim3(1024), 0, stream, pos, startB, idx);
  hipLaunchKernelGGL(perm_kernel, dim3(2 * NB), dim3(1024), 0, stream, sub1, sub2, v1, idx);
  hipLaunchKernelGGL(possub_kernel, dim3((NB * 3 * NM + 255) / 256), dim3(256), 0, stream,
                     pos, idx, v1, posOut);
  hipLaunchKernelGGL(transpose_kernel, dim3(NN / 32, NC / 32, NB), dim3(32, 32), 0, stream,
                     x, xT);
  hipLaunchKernelGGL(knn_kernel, dim3(NB * NM / 4), dim3(256), 0, stream, pos, posOut, knn);
  hipLaunchKernelGGL(final_kernel, dim3(NB * NM / 16), dim3(256), 0, stream,
                     xT, pos, posOut, knn, xOut);
}

// Round 3
// 2248.291 us; speedup vs baseline: 1.0095x; 1.0095x over previous
//
#include <hip/hip_runtime.h>

// Problem constants (match reference)
constexpr int NB   = 8;     // batches
constexpr int NC   = 64;    // channels
constexpr int NN   = 8192;  // points
constexpr int NM   = 2048;  // samples
constexpr int NK   = 16;    // knn
constexpr int NFPS = 1433;  // int(2048*0.7)
constexpr int NRAND = NM - NFPS; // 615

// ---------------- workspace layout (bytes) ----------------
constexpr size_t OFF_START = 0;
constexpr size_t OFF_SUB1  = 64;
constexpr size_t OFF_SUB2  = 128;
constexpr size_t OFF_IDX   = 256;      // int idx[8][2048]
constexpr size_t OFF_V1    = 66048;    // uint v1[8][8192]
constexpr size_t OFF_KNN   = 328448;   // int knn[8][2048][16]
constexpr size_t OFF_XT    = 1377280;  // float xT[8][8192][64]

typedef float v2f __attribute__((ext_vector_type(2)));

struct TF { unsigned a, b; };

__device__ __forceinline__ TF tf2(unsigned k0, unsigned k1, unsigned c0, unsigned c1) {
  unsigned ks2 = k0 ^ k1 ^ 0x1BD11BDAu;
  unsigned x0 = c0 + k0;
  unsigned x1 = c1 + k1;
#define TF_R(r) { x0 += x1; x1 = (x1 << r) | (x1 >> (32 - r)); x1 ^= x0; }
  TF_R(13) TF_R(15) TF_R(26) TF_R(6)
  x0 += k1;  x1 += ks2 + 1u;
  TF_R(17) TF_R(29) TF_R(16) TF_R(24)
  x0 += ks2; x1 += k0 + 2u;
  TF_R(13) TF_R(15) TF_R(26) TF_R(6)
  x0 += k0;  x1 += k1 + 3u;
  TF_R(17) TF_R(29) TF_R(16) TF_R(24)
  x0 += k1;  x1 += ks2 + 4u;
  TF_R(13) TF_R(15) TF_R(26) TF_R(6)
  x0 += ks2; x1 += k0 + 5u;
#undef TF_R
  TF r; r.a = x0; r.b = x1; return r;
}

// ---------------- PRNG setup (jax_threefry_partitionable=True, verified R1) ----------------
__global__ void rng_setup(unsigned* __restrict__ startB,
                          unsigned* __restrict__ sub1,
                          unsigned* __restrict__ sub2) {
  if (threadIdx.x != 0) return;
  const unsigned K0 = 0u, K1 = 42u; // jax.random.key(42)
  for (int b = 0; b < NB; ++b) {
    TF kb = tf2(K0, K1, 0u, (unsigned)b);
    TF k2 = tf2(kb.a, kb.b, 0u, 1u);
    TF bt = tf2(k2.a, k2.b, 0u, 0u);
    startB[b] = (bt.a ^ bt.b) & (unsigned)(NN - 1);
  }
  TF keyr = tf2(K0, K1, 0u, 1u); // fold_in(key42, 1)
  for (int b = 0; b < NB; ++b) {
    TF rk = tf2(keyr.a, keyr.b, 0u, (unsigned)b);   // rkeys[b]
    TF s1 = tf2(rk.a, rk.b, 0u, 1u);                // round-1 subkey
    TF nk = tf2(rk.a, rk.b, 0u, 0u);                // round-1 carried key
    TF s2 = tf2(nk.a, nk.b, 0u, 1u);                // round-2 subkey
    sub1[2*b] = s1.a; sub1[2*b+1] = s1.b;
    sub2[2*b] = s2.a; sub2[2*b+1] = s2.b;
  }
}

// DPP-based wave64 max (VALU latency, no LDS on the chain).
// row_shr:1/2/4/8 build per-row(16) prefix max; row_bcast15 (rows 1,3) and
// row_bcast31 (rows 2,3) merge rows; lane 63 holds the full-wave max.
__device__ __forceinline__ float wave_max_dpp(float v) {
  int vi;
  vi = __builtin_amdgcn_update_dpp(__float_as_int(v), __float_as_int(v), 0x111, 0xf, 0xf, false);
  v = fmaxf(v, __int_as_float(vi));
  vi = __builtin_amdgcn_update_dpp(__float_as_int(v), __float_as_int(v), 0x112, 0xf, 0xf, false);
  v = fmaxf(v, __int_as_float(vi));
  vi = __builtin_amdgcn_update_dpp(__float_as_int(v), __float_as_int(v), 0x114, 0xf, 0xf, false);
  v = fmaxf(v, __int_as_float(vi));
  vi = __builtin_amdgcn_update_dpp(__float_as_int(v), __float_as_int(v), 0x118, 0xf, 0xf, false);
  v = fmaxf(v, __int_as_float(vi));
  vi = __builtin_amdgcn_update_dpp(__float_as_int(v), __float_as_int(v), 0x142, 0xa, 0xf, false);
  v = fmaxf(v, __int_as_float(vi));
  vi = __builtin_amdgcn_update_dpp(__float_as_int(v), __float_as_int(v), 0x143, 0xc, 0xf, false);
  v = fmaxf(v, __int_as_float(vi));
  return __int_as_float(__builtin_amdgcn_readlane(__float_as_int(v), 63));
}

// 3-step DPP row(16) prefix-max (f32). With 8 distinct values replicated at
// lane&7, lane 7 of every 16-lane row holds the max over all 8 slots.
__device__ __forceinline__ float row_prefix_max8_f32(float v) {
  int vi;
  vi = __builtin_amdgcn_update_dpp(__float_as_int(v), __float_as_int(v), 0x111, 0xf, 0xf, false);
  v = fmaxf(v, __int_as_float(vi));
  vi = __builtin_amdgcn_update_dpp(__float_as_int(v), __float_as_int(v), 0x112, 0xf, 0xf, false);
  v = fmaxf(v, __int_as_float(vi));
  vi = __builtin_amdgcn_update_dpp(__float_as_int(v), __float_as_int(v), 0x114, 0xf, 0xf, false);
  v = fmaxf(v, __int_as_float(vi));
  return v;
}

// ---------------- FPS: one block (512 thr, 8 waves, 2/SIMD) per batch ----------------
// 1432 serial argmax steps, issue-bound on 8 CUs (R2 post-mortem: VALUBusy at
// 89.5% of the 8-CU ceiling). This version minimizes per-CU instructions:
//  - packed-f32 slot-pair update (v_pk_mul/add, fp contract off => bit-exact
//    mul+add identical to scalar __fmul_rn/__fadd_rn per half)
//  - no inline argmax-index tracking; recover index after the wave max via
//    16 per-slot cmp-ballots (VALU) + SALU min of lane*16+s (co-issued)
//  - slot merge: ds_read_b64 of (idx, valuebits) + 3-step f32 DPP prefix max
//    + ballot/ctz (smallest tying slot = smallest index, wave order ==
//    index order) + readlane
// Tie-break = first index exactly, at every level (slot scan ascending,
// ballot ctz = lowest lane, smallest slot wins merge ties).
__global__ __launch_bounds__(512, 2) void fps_kernel(const float* __restrict__ pos,
                                                     const unsigned* __restrict__ startB,
                                                     int* __restrict__ idx) {
  __shared__ float ldsX[NN];   // 32 KB
  __shared__ float ldsY[NN];   // 32 KB
  __shared__ float ldsZ[NN];   // 32 KB
  __shared__ uint2 slot2[2][8];
  const int b = blockIdx.x;
  const int tid = threadIdx.x;
  const int wv = tid >> 6, lane = tid & 63;
  const float* pb = pos + (size_t)b * 3 * NN;
  constexpr int SLOTS = NN / 512;   // 16
  constexpr int PAIRS = SLOTS / 2;  // 8
  v2f px[PAIRS], py[PAIRS], pz[PAIRS];
  float dist[SLOTS];
  const int base = tid * SLOTS;   // tid-major ownership => lane order == index order
  const float4* fx = (const float4*)(pb + base);
  const float4* fy = (const float4*)(pb + NN + base);
  const float4* fz = (const float4*)(pb + 2 * NN + base);
#pragma unroll
  for (int q = 0; q < SLOTS / 4; ++q) {
    float4 a = fx[q], c = fy[q], e = fz[q];
    px[2*q].x = a.x; px[2*q].y = a.y; px[2*q+1].x = a.z; px[2*q+1].y = a.w;
    py[2*q].x = c.x; py[2*q].y = c.y; py[2*q+1].x = c.z; py[2*q+1].y = c.w;
    pz[2*q].x = e.x; pz[2*q].y = e.y; pz[2*q+1].x = e.z; pz[2*q+1].y = e.w;
    ((float4*)(ldsX + base))[q] = a;   // one-time stage (conflicts OK, ~1 µs)
    ((float4*)(ldsY + base))[q] = c;
    ((float4*)(ldsZ + base))[q] = e;
  }
#pragma unroll
  for (int s = 0; s < SLOTS; ++s) dist[s] = 1e10f;
  int widx = (int)startB[b];
  if (tid == 0) idx[b * NM] = widx;
  __syncthreads();
  float cx = ldsX[widx], cy = ldsY[widx], cz = ldsZ[widx];
  for (int it = 1; it < NFPS; ++it) {
    const int par = it & 1;
    float bestv = -1.0f;
    {
      v2f cxx; cxx.x = cx; cxx.y = cx;
      v2f cyy; cyy.x = cy; cyy.y = cy;
      v2f czz; czz.x = cz; czz.y = cz;
#pragma unroll
      for (int p = 0; p < PAIRS; ++p) {
        // Mirror numpy/XLA exactly per half: rn ops, NO fma contraction,
        // ((dx2+dy2)+dz2). contract(off) keeps pk_mul/pk_add separate.
#pragma clang fp contract(off)
        v2f dx = px[p] - cxx;
        v2f dy = py[p] - cyy;
        v2f dz = pz[p] - czz;
        v2f d2 = (dx * dx + dy * dy) + dz * dz;
        float nd0 = fminf(dist[2*p],     d2.x);
        float nd1 = fminf(dist[2*p + 1], d2.y);
        dist[2*p] = nd0; dist[2*p + 1] = nd1;
        bestv = fmaxf(fmaxf(bestv, nd0), nd1);   // -> v_max3_f32
      }
    }
    const float wm = wave_max_dpp(bestv);
    // per-wave argmax index: per-slot ballots; min of lane*SLOTS+s on SALU.
    // Ascending s + ctz(lowest lane) + unsigned min == first (smallest) index.
    unsigned bestRel = 0xFFFFFFFFu;
#pragma unroll
    for (int s = 0; s < SLOTS; ++s) {
      unsigned long long m = __ballot(dist[s] == wm);
      unsigned long long mm = m ? m : 1ull;  // guard ctz(0) UB; discarded below
      unsigned cand = m ? ((unsigned)__builtin_ctzll(mm) * (unsigned)SLOTS + (unsigned)s)
                        : 0xFFFFFFFFu;
      bestRel = (cand < bestRel) ? cand : bestRel;
    }
    const int widxw = wv * (64 * SLOTS) + (int)bestRel;
    if (lane == 0)
      slot2[par][wv] = make_uint2((unsigned)widxw, __float_as_uint(wm));
    __syncthreads();
    // block merge: broadcast-read 8 wave composites, f32 DPP prefix max,
    // smallest tying slot (== smallest index) via ballot/ctz, readlane idx.
    uint2 sv = slot2[par][lane & 7];
    float v = __uint_as_float(sv.y);
    float pv = row_prefix_max8_f32(v);
    const float bm = __int_as_float(__builtin_amdgcn_readlane(__float_as_int(pv), 7));
    unsigned long long wb = __ballot(v == bm);   // nonzero by construction
    const int w0 = (int)__builtin_ctzll(wb);     // smallest slot = smallest index
    widx = __builtin_amdgcn_readlane((int)sv.x, w0);
    cx = ldsX[widx]; cy = ldsY[widx]; cz = ldsZ[widx];  // uniform broadcast reads
    if (tid == 0) idx[b * NM + it] = widx;
  }
}

// ---------------- permutation: 2 independent stable sorts, 16 blocks ----------------
__device__ void bitonic8192(unsigned long long* s, int tid) {
  for (unsigned k = 2; k <= 8192u; k <<= 1) {
    for (unsigned j = k >> 1; j > 0; j >>= 1) {
      __syncthreads();
      for (unsigned t = (unsigned)tid; t < 4096u; t += 1024u) {
        unsigned i = ((t & ~(j - 1u)) << 1) | (t & (j - 1u));
        unsigned p = i | j;
        bool up = ((i & k) == 0u);
        unsigned long long a = s[i], c = s[p];
        if ((a > c) == up) { s[i] = c; s[p] = a; }
      }
    }
  }
  __syncthreads();
}

// block = (batch, round). Round 0 writes the full round-1 permutation v1;
// round 1 writes its first NRAND payload positions into idx (composed later).
__global__ __launch_bounds__(1024) void perm_kernel(const unsigned* __restrict__ sub1,
                                                    const unsigned* __restrict__ sub2,
                                                    unsigned* __restrict__ v1buf,
                                                    int* __restrict__ idx) {
  __shared__ unsigned long long s[NN]; // 64 KB
  const int bl = blockIdx.x;
  const int b = bl >> 1, r = bl & 1;
  const int tid = threadIdx.x;
  const unsigned* sk = (r == 0) ? sub1 : sub2;
  const unsigned ka = sk[2*b], kb = sk[2*b+1];
  for (int i = tid; i < NN; i += 1024) {
    TF t = tf2(ka, kb, 0u, (unsigned)i);
    // composite (key<<32)|position => stable sort incl. key collisions
    s[i] = ((unsigned long long)(t.a ^ t.b) << 32) | (unsigned)i;
  }
  bitonic8192(s, tid);
  if (r == 0) {
    unsigned* v1 = v1buf + (size_t)b * NN;
    for (int i = tid; i < NN; i += 1024) v1[i] = (unsigned)(s[i] & 0xffffffffu);
  } else {
    for (int t = tid; t < NRAND; t += 1024)
      idx[b * NM + NFPS + t] = (int)(s[t] & 0xffffffffu);
  }
}

// ---------------- pos_sub gather (composes v1[v2] for the random part) ----------------
__global__ void possub_kernel(const float* __restrict__ pos,
                              const int* __restrict__ idx,
                              const unsigned* __restrict__ v1,
                              float* __restrict__ posOut) {
  int i = blockIdx.x * 256 + threadIdx.x;
  if (i >= NB * 3 * NM) return;
  int mm = i & (NM - 1);
  int bd = i >> 11;            // b*3 + d
  int d = bd % 3, b = bd / 3;
  int raw = idx[b * NM + mm];
  int id = (mm < NFPS) ? raw : (int)v1[(size_t)b * NN + raw];
  posOut[i] = pos[((size_t)b * 3 + d) * NN + id];
}

// ---------------- transpose x [B,C,N] -> xT [B,N,C] ----------------
__global__ void transpose_kernel(const float* __restrict__ x, float* __restrict__ xT) {
  __shared__ float t[32][33];
  int b = blockIdx.z;
  int n0 = blockIdx.x * 32, c0 = blockIdx.y * 32;
  int tx = threadIdx.x, ty = threadIdx.y;
  t[ty][tx] = x[((size_t)b * NC + (c0 + ty)) * NN + n0 + tx];
  __syncthreads();
  xT[((size_t)b * NN + (n0 + ty)) * NC + c0 + tx] = t[tx][ty];
}

// ---------------- KNN: one wave per sampled point ----------------
// Per-lane top-16 in registers (branchless v_med3 chain); LDS only for the
// final 64-list wave merge (verified R3).
__global__ __launch_bounds__(256) void knn_kernel(const float* __restrict__ pos,
                                                  const float* __restrict__ posSub,
                                                  int* __restrict__ knn) {
  __shared__ unsigned long long lst[4][NK][64]; // [wave][rank][lane], 32 KB
  const int tid = threadIdx.x;
  const int wv = tid >> 6, lane = tid & 63;
  const int g = blockIdx.x * 4 + wv;            // 0..16383
  const int b = g >> 11, mm = g & (NM - 1);
  const float* pb = pos + (size_t)b * 3 * NN;
  const float* ps = posSub + (size_t)b * 3 * NM;
  const float sx = ps[mm], sy = ps[NM + mm], sz = ps[2 * NM + mm];
  const float sm = __fadd_rn(__fadd_rn(__fmul_rn(sx, sx), __fmul_rn(sy, sy)),
                             __fmul_rn(sz, sz));
  float key[NK]; int kid[NK];
#pragma unroll
  for (int i = 0; i < NK; ++i) { key[i] = __int_as_float(0x7F800000); kid[i] = 0; }
  for (int t = 0; t < NN / 64; ++t) {
    const int n = t * 64 + lane;
    float x = pb[n], y = pb[NN + n], z = pb[2 * NN + n];
    float sn = __fadd_rn(__fadd_rn(__fmul_rn(x, x), __fmul_rn(y, y)), __fmul_rn(z, z));
    float dt = __fadd_rn(__fadd_rn(__fmul_rn(sx, x), __fmul_rn(sy, y)), __fmul_rn(sz, z));
    float d2 = __fsub_rn(__fadd_rn(sm, sn), __fmul_rn(2.0f, dt)); // mirror reference
    const float ck = d2; const int ci = n;
    // branchless sorted insert, descending so olds are read before overwrite;
    // strict < => equal keys keep earlier (smaller-index) candidate first
#pragma unroll
    for (int i = NK - 1; i >= 1; --i) {
      float lo = key[i-1], hi = key[i];
      bool cLo = ck < lo, cHi = ck < hi;
      key[i] = __builtin_amdgcn_fmed3f(ck, lo, hi);
      kid[i] = cLo ? kid[i-1] : (cHi ? ci : kid[i]);
    }
    bool c0 = ck < key[0];
    kid[0] = c0 ? ci : kid[0];
    key[0] = fminf(key[0], ck);
  }
  // dump sorted lists (order-flipped keys) to LDS; same-wave access, no barrier
#pragma unroll
  for (int i = 0; i < NK; ++i) {
    unsigned u = __float_as_uint(key[i]);
    u = (u & 0x80000000u) ? ~u : (u | 0x80000000u);
    lst[wv][i][lane] = ((unsigned long long)u << 32) | (unsigned)kid[i];
  }
  // merge 64 sorted lists: 16 rounds of wave-min; unique composites => safe pop
  int ptr = 0;
  unsigned long long head = lst[wv][0][lane];
  unsigned myn = 0;
  for (int k = 0; k < NK; ++k) {
    unsigned long long mn = head;
#pragma unroll
    for (int off = 32; off > 0; off >>= 1) {
      unsigned long long o = __shfl_xor(mn, off, 64);
      if (o < mn) mn = o;
    }
    if (head == mn) { ++ptr; head = (ptr < NK) ? lst[wv][ptr][lane] : ~0ull; }
    if (lane == k) myn = (unsigned)(mn & 0xffffffffu);
  }
  if (lane < NK) knn[(size_t)g * NK + lane] = (int)myn;
}

// ---------------- weights + gather + weighted sum ----------------
__global__ __launch_bounds__(256) void final_kernel(const float* __restrict__ xT,
                                                    const float* __restrict__ pos,
                                                    const float* __restrict__ posSub,
                                                    const int* __restrict__ knn,
                                                    float* __restrict__ xOut) {
  __shared__ float tile[64][17];
  const int tid = threadIdx.x;
  const int wv = tid >> 6, lane = tid & 63;
  const int base = blockIdx.x * 16;      // 16 consecutive samples, same batch
  const int b = base >> 11;
  const float* pb = pos + (size_t)b * 3 * NN;
  const float* ps = posSub + (size_t)b * 3 * NM;
  for (int j = 0; j < 4; ++j) {
    const int ml = wv * 4 + j;           // 0..15
    const int g = base + ml;
    const int mm = g & (NM - 1);
    const float sx = ps[mm], sy = ps[NM + mm], sz = ps[2 * NM + mm];
    const int kk = lane & 15;
    const int nk = knn[(size_t)g * NK + kk];
    float dx = __fsub_rn(pb[nk], sx);
    float dy = __fsub_rn(pb[NN + nk], sy);
    float dz = __fsub_rn(pb[2 * NN + nk], sz);
    float dd = __fadd_rn(__fadd_rn(__fmul_rn(dx, dx), __fmul_rn(dy, dy)),
                         __fmul_rn(dz, dz));
    float d = __fsqrt_rn(dd);
    d = fmaxf(d, 1e-6f);
    float e = __fdiv_rn(0.0f - d, 0.2f);
    float mx = e;
#pragma unroll
    for (int off = 8; off > 0; off >>= 1) mx = fmaxf(mx, __shfl_xor(mx, off, 16));
    float ex = expf(__fsub_rn(e, mx));
    float sum = ex;
#pragma unroll
    for (int off = 8; off > 0; off >>= 1) sum = __fadd_rn(sum, __shfl_xor(sum, off, 16));
    float wgt = __fdiv_rn(ex, sum);
    float acc = 0.0f;
#pragma unroll
    for (int k = 0; k < NK; ++k) {
      float wk = __shfl(wgt, k, 64);
      int   nn = __shfl(nk, k, 64);
      acc = __fadd_rn(acc, __fmul_rn(wk, xT[((size_t)b * NN + nn) * NC + lane]));
    }
    tile[lane][ml] = acc;
  }
  __syncthreads();
  const int m0 = base & (NM - 1);
  for (int e2 = tid; e2 < 64 * 16; e2 += 256) {
    int c = e2 >> 4, ml = e2 & 15;
    xOut[((size_t)b * NC + c) * NM + m0 + ml] = tile[c][ml];
  }
}

extern "C" void kernel_launch(void* const* d_in, const int* in_sizes, int n_in,
                              void* d_out, int out_size, void* d_ws, size_t ws_size,
                              hipStream_t stream) {
  const float* x   = (const float*)d_in[0];
  const float* pos = (const float*)d_in[1];
  float* xOut   = (float*)d_out;
  float* posOut = xOut + (size_t)NB * NC * NM;

  char* w = (char*)d_ws;
  unsigned* startB = (unsigned*)(w + OFF_START);
  unsigned* sub1   = (unsigned*)(w + OFF_SUB1);
  unsigned* sub2   = (unsigned*)(w + OFF_SUB2);
  int*      idx    = (int*)(w + OFF_IDX);
  unsigned* v1     = (unsigned*)(w + OFF_V1);
  int*      knn    = (int*)(w + OFF_KNN);
  float*    xT     = (float*)(w + OFF_XT);

  hipLaunchKernelGGL(rng_setup, dim3(1), dim3(64), 0, stream, startB, sub1, sub2);
  hipLaunchKernelGGL(fps_kernel, dim3(NB), dim3(512), 0, stream, pos, startB, idx);
  hipLaunchKernelGGL(perm_kernel, dim3(2 * NB), dim3(1024), 0, stream, sub1, sub2, v1, idx);
  hipLaunchKernelGGL(possub_kernel, dim3((NB * 3 * NM + 255) / 256), dim3(256), 0, stream,
                     pos, idx, v1, posOut);
  hipLaunchKernelGGL(transpose_kernel, dim3(NN / 32, NC / 32, NB), dim3(32, 32), 0, stream,
                     x, xT);
  hipLaunchKernelGGL(knn_kernel, dim3(NB * NM / 4), dim3(256), 0, stream, pos, posOut, knn);
  hipLaunchKernelGGL(final_kernel, dim3(NB * NM / 16), dim3(256), 0, stream,
                     xT, pos, posOut, knn, xOut);
}

// Round 4
// 1814.318 us; speedup vs baseline: 1.2510x; 1.2392x over previous
//
#include <hip/hip_runtime.h>

// Problem constants (match reference)
constexpr int NB   = 8;     // batches
constexpr int NC   = 64;    // channels
constexpr int NN   = 8192;  // points
constexpr int NM   = 2048;  // samples
constexpr int NK   = 16;    // knn
constexpr int NFPS = 1433;  // int(2048*0.7)
constexpr int NRAND = NM - NFPS; // 615

// ---------------- workspace layout (bytes) ----------------
constexpr size_t OFF_IDX   = 256;      // int idx[8][2048]
constexpr size_t OFF_V1    = 66048;    // uint v1[8][8192]
constexpr size_t OFF_KNN   = 328448;   // int knn[8][2048][16]
constexpr size_t OFF_XT    = 1377280;  // float xT[8][8192][64]

struct TF { unsigned a, b; };

__device__ __forceinline__ TF tf2(unsigned k0, unsigned k1, unsigned c0, unsigned c1) {
  unsigned ks2 = k0 ^ k1 ^ 0x1BD11BDAu;
  unsigned x0 = c0 + k0;
  unsigned x1 = c1 + k1;
#define TF_R(r) { x0 += x1; x1 = (x1 << r) | (x1 >> (32 - r)); x1 ^= x0; }
  TF_R(13) TF_R(15) TF_R(26) TF_R(6)
  x0 += k1;  x1 += ks2 + 1u;
  TF_R(17) TF_R(29) TF_R(16) TF_R(24)
  x0 += ks2; x1 += k0 + 2u;
  TF_R(13) TF_R(15) TF_R(26) TF_R(6)
  x0 += k0;  x1 += k1 + 3u;
  TF_R(17) TF_R(29) TF_R(16) TF_R(24)
  x0 += k1;  x1 += ks2 + 4u;
  TF_R(13) TF_R(15) TF_R(26) TF_R(6)
  x0 += ks2; x1 += k0 + 5u;
#undef TF_R
  TF r; r.a = x0; r.b = x1; return r;
}

// DPP-based wave64 max (VALU latency, no LDS on the chain).
__device__ __forceinline__ float wave_max_dpp(float v) {
  int vi;
  vi = __builtin_amdgcn_update_dpp(__float_as_int(v), __float_as_int(v), 0x111, 0xf, 0xf, false);
  v = fmaxf(v, __int_as_float(vi));
  vi = __builtin_amdgcn_update_dpp(__float_as_int(v), __float_as_int(v), 0x112, 0xf, 0xf, false);
  v = fmaxf(v, __int_as_float(vi));
  vi = __builtin_amdgcn_update_dpp(__float_as_int(v), __float_as_int(v), 0x114, 0xf, 0xf, false);
  v = fmaxf(v, __int_as_float(vi));
  vi = __builtin_amdgcn_update_dpp(__float_as_int(v), __float_as_int(v), 0x118, 0xf, 0xf, false);
  v = fmaxf(v, __int_as_float(vi));
  vi = __builtin_amdgcn_update_dpp(__float_as_int(v), __float_as_int(v), 0x142, 0xa, 0xf, false);
  v = fmaxf(v, __int_as_float(vi));
  vi = __builtin_amdgcn_update_dpp(__float_as_int(v), __float_as_int(v), 0x143, 0xc, 0xf, false);
  v = fmaxf(v, __int_as_float(vi));
  return __int_as_float(__builtin_amdgcn_readlane(__float_as_int(v), 63));
}

// ---------------- fused1: fps (blocks 0-7) + perm (8-23) + transpose (24-4119) ----
// fps occupies only 8 CUs for ~1.25 ms; perm and transpose have NO dependence
// on fps (disjoint outputs: idx[0:NFPS] vs idx[NFPS:]+v1 vs xT) and stream
// through the other 248 CUs inside fps's shadow. No inter-block communication
// anywhere -> dispatch-order independent (G16-safe). LDS = union (98.4 KB).
constexpr int FPS_BLKS = NB;                 // 8
constexpr int PERM_BLKS = 2 * NB;            // 16
constexpr int TR_BLKS = (NN / 32) * (NC / 32) * NB;  // 4096

// bitonic sort over 8192 u64 in LDS, 256 threads (16 pairs/thread/stage)
__device__ void bitonic8192_256(unsigned long long* s, int tid) {
  for (unsigned k = 2; k <= 8192u; k <<= 1) {
    for (unsigned j = k >> 1; j > 0; j >>= 1) {
      __syncthreads();
      for (unsigned t = (unsigned)tid; t < 4096u; t += 256u) {
        unsigned i = ((t & ~(j - 1u)) << 1) | (t & (j - 1u));
        unsigned p = i | j;
        bool up = ((i & k) == 0u);
        unsigned long long a = s[i], c = s[p];
        if ((a > c) == up) { s[i] = c; s[p] = a; }
      }
    }
  }
  __syncthreads();
}

__global__ __launch_bounds__(256, 1) void fused1_kernel(const float* __restrict__ pos,
                                                        const float* __restrict__ x,
                                                        int* __restrict__ idx,
                                                        unsigned* __restrict__ v1buf,
                                                        float* __restrict__ xT) {
  __shared__ __align__(16) char smem[98432];
  const int bid = blockIdx.x;
  const int tid = threadIdx.x;

  if (bid < FPS_BLKS) {
    // ================= FPS: proven R0 config (256 thr, 4 waves) =================
    float* ldsX = (float*)smem;                       // 32 KB
    float* ldsY = (float*)(smem + 32768);             // 32 KB
    float* ldsZ = (float*)(smem + 65536);             // 32 KB
    float2 (*slot)[4] = (float2(*)[4])(smem + 98304); // [2][4]
    const int b = bid;
    const int wv = tid >> 6, lane = tid & 63;
    const float* pb = pos + (size_t)b * 3 * NN;
    float px[32], py[32], pz[32], dist[32];
    const int base = tid * 32;   // tid-major ownership => lane order == index order
    const float4* fx = (const float4*)(pb + base);
    const float4* fy = (const float4*)(pb + NN + base);
    const float4* fz = (const float4*)(pb + 2 * NN + base);
#pragma unroll
    for (int q = 0; q < 8; ++q) {
      float4 a = fx[q], c = fy[q], e = fz[q];
      px[4*q] = a.x; px[4*q+1] = a.y; px[4*q+2] = a.z; px[4*q+3] = a.w;
      py[4*q] = c.x; py[4*q+1] = c.y; py[4*q+2] = c.z; py[4*q+3] = c.w;
      pz[4*q] = e.x; pz[4*q+1] = e.y; pz[4*q+2] = e.z; pz[4*q+3] = e.w;
      ((float4*)(ldsX + base))[q] = a;   // one-time stage
      ((float4*)(ldsY + base))[q] = c;
      ((float4*)(ldsZ + base))[q] = e;
    }
#pragma unroll
    for (int s = 0; s < 32; ++s) dist[s] = 1e10f;
    // inline start index (was rng_setup): jax.random.key(42) -> keys[b] -> randint
    TF kb_ = tf2(0u, 42u, 0u, (unsigned)b);
    TF k2 = tf2(kb_.a, kb_.b, 0u, 1u);
    TF bt = tf2(k2.a, k2.b, 0u, 0u);
    int widx = (int)((bt.a ^ bt.b) & (unsigned)(NN - 1));
    if (tid == 0) idx[b * NM] = widx;
    __syncthreads();
    float cx = ldsX[widx], cy = ldsY[widx], cz = ldsZ[widx];
    for (int it = 1; it < NFPS; ++it) {
      const int par = it & 1;
      float bestv = -1.0f; int bestS = 0;
#pragma unroll
      for (int s = 0; s < 32; ++s) {
        // Mirror numpy/XLA exactly: rn ops, no FMA contraction, ((dx2+dy2)+dz2)
        float dx = __fsub_rn(px[s], cx);
        float dy = __fsub_rn(py[s], cy);
        float dz = __fsub_rn(pz[s], cz);
        float d  = __fadd_rn(__fadd_rn(__fmul_rn(dx, dx), __fmul_rn(dy, dy)),
                             __fmul_rn(dz, dz));
        float nd = fminf(dist[s], d);
        dist[s] = nd;
        bool c = nd > bestv;            // strict > keeps first (smallest) index
        bestv = c ? nd : bestv;
        bestS = c ? s : bestS;
      }
      const int gidx = base + bestS;
      const float wm = wave_max_dpp(bestv);
      unsigned long long msk = __ballot(bestv == wm);  // nonzero: max lane matches
      const int fl = (int)__builtin_ctzll(msk);        // lowest lane = smallest index
      const int widxw = __builtin_amdgcn_readlane(gidx, fl);
      if (lane == 0) slot[par][wv] = make_float2(wm, __int_as_float(widxw));
      __syncthreads();
      float2 s0 = slot[par][0], s1 = slot[par][1], s2 = slot[par][2], s3 = slot[par][3];
      if (s1.x > s0.x) s0 = s1;     // ties keep lower wave = smaller index
      if (s3.x > s2.x) s2 = s3;
      if (s2.x > s0.x) s0 = s2;
      widx = __float_as_int(s0.y);
      cx = ldsX[widx]; cy = ldsY[widx]; cz = ldsZ[widx];  // uniform broadcast reads
      if (tid == 0) idx[b * NM + it] = widx;
    }
  } else if (bid < FPS_BLKS + PERM_BLKS) {
    // ================= permutation sorts (round 0: v1, round 1: rand idx) =======
    unsigned long long* s = (unsigned long long*)smem; // 64 KB
    const int pbl = bid - FPS_BLKS;
    const int b = pbl >> 1, r = pbl & 1;
    // inline subkeys (was rng_setup): fold_in(key42,1) -> rkeys[b] -> rounds
    TF keyr = tf2(0u, 42u, 0u, 1u);
    TF rk = tf2(keyr.a, keyr.b, 0u, (unsigned)b);
    TF s1k = tf2(rk.a, rk.b, 0u, 1u);                // round-1 subkey
    TF nk  = tf2(rk.a, rk.b, 0u, 0u);                // round-1 carried key
    TF s2k = tf2(nk.a, nk.b, 0u, 1u);                // round-2 subkey
    const unsigned ka = r ? s2k.a : s1k.a;
    const unsigned kb = r ? s2k.b : s1k.b;
    for (int i = tid; i < NN; i += 256) {
      TF t = tf2(ka, kb, 0u, (unsigned)i);
      // composite (key<<32)|position => stable sort incl. key collisions
      s[i] = ((unsigned long long)(t.a ^ t.b) << 32) | (unsigned)i;
    }
    bitonic8192_256(s, tid);
    if (r == 0) {
      unsigned* v1 = v1buf + (size_t)b * NN;
      for (int i = tid; i < NN; i += 256) v1[i] = (unsigned)(s[i] & 0xffffffffu);
    } else {
      for (int t = tid; t < NRAND; t += 256)
        idx[b * NM + NFPS + t] = (int)(s[t] & 0xffffffffu);
    }
  } else {
    // ================= transpose x [B,C,N] -> xT [B,N,C] ========================
    float (*t)[33] = (float(*)[33])smem;
    const int tt = bid - (FPS_BLKS + PERM_BLKS);
    const int n0 = (tt & 255) * 32;
    const int c0 = ((tt >> 8) & 1) * 32;
    const int b = tt >> 9;
    const int tx = tid & 31, ty0 = tid >> 5;  // 32 x 8
#pragma unroll
    for (int r = 0; r < 4; ++r) {
      const int ty = ty0 + r * 8;
      t[ty][tx] = x[((size_t)b * NC + (c0 + ty)) * NN + n0 + tx];
    }
    __syncthreads();
#pragma unroll
    for (int r = 0; r < 4; ++r) {
      const int ty = ty0 + r * 8;
      xT[((size_t)b * NN + (n0 + ty)) * NC + c0 + tx] = t[tx][ty];
    }
  }
}

// ---------------- KNN: one wave per sampled point (self-gathers its sample) ----
// Sample coords gathered directly from pos via idx/v1 -> bit-identical to the
// possub buffer values; removes the possub->knn serial dependency.
__global__ __launch_bounds__(256) void knn_kernel(const float* __restrict__ pos,
                                                  const int* __restrict__ idx,
                                                  const unsigned* __restrict__ v1,
                                                  int* __restrict__ knn) {
  __shared__ unsigned long long lst[4][NK][64]; // [wave][rank][lane], 32 KB
  const int tid = threadIdx.x;
  const int wv = tid >> 6, lane = tid & 63;
  const int g = blockIdx.x * 4 + wv;            // 0..16383
  const int b = g >> 11, mm = g & (NM - 1);
  const float* pb = pos + (size_t)b * 3 * NN;
  const int raw = idx[b * NM + mm];
  const int id = (mm < NFPS) ? raw : (int)v1[(size_t)b * NN + raw];
  const float sx = pb[id], sy = pb[NN + id], sz = pb[2 * NN + id];
  const float sm = __fadd_rn(__fadd_rn(__fmul_rn(sx, sx), __fmul_rn(sy, sy)),
                             __fmul_rn(sz, sz));
  float key[NK]; int kid[NK];
#pragma unroll
  for (int i = 0; i < NK; ++i) { key[i] = __int_as_float(0x7F800000); kid[i] = 0; }
  for (int t = 0; t < NN / 64; ++t) {
    const int n = t * 64 + lane;
    float x = pb[n], y = pb[NN + n], z = pb[2 * NN + n];
    float sn = __fadd_rn(__fadd_rn(__fmul_rn(x, x), __fmul_rn(y, y)), __fmul_rn(z, z));
    float dt = __fadd_rn(__fadd_rn(__fmul_rn(sx, x), __fmul_rn(sy, y)), __fmul_rn(sz, z));
    float d2 = __fsub_rn(__fadd_rn(sm, sn), __fmul_rn(2.0f, dt)); // mirror reference
    const float ck = d2; const int ci = n;
    // branchless sorted insert, descending so olds are read before overwrite;
    // strict < => equal keys keep earlier (smaller-index) candidate first
#pragma unroll
    for (int i = NK - 1; i >= 1; --i) {
      float lo = key[i-1], hi = key[i];
      bool cLo = ck < lo, cHi = ck < hi;
      key[i] = __builtin_amdgcn_fmed3f(ck, lo, hi);
      kid[i] = cLo ? kid[i-1] : (cHi ? ci : kid[i]);
    }
    bool c0 = ck < key[0];
    kid[0] = c0 ? ci : kid[0];
    key[0] = fminf(key[0], ck);
  }
  // dump sorted lists (order-flipped keys) to LDS; same-wave access, no barrier
#pragma unroll
  for (int i = 0; i < NK; ++i) {
    unsigned u = __float_as_uint(key[i]);
    u = (u & 0x80000000u) ? ~u : (u | 0x80000000u);
    lst[wv][i][lane] = ((unsigned long long)u << 32) | (unsigned)kid[i];
  }
  // merge 64 sorted lists: 16 rounds of wave-min; unique composites => safe pop
  int ptr = 0;
  unsigned long long head = lst[wv][0][lane];
  unsigned myn = 0;
  for (int k = 0; k < NK; ++k) {
    unsigned long long mn = head;
#pragma unroll
    for (int off = 32; off > 0; off >>= 1) {
      unsigned long long o = __shfl_xor(mn, off, 64);
      if (o < mn) mn = o;
    }
    if (head == mn) { ++ptr; head = (ptr < NK) ? lst[wv][ptr][lane] : ~0ull; }
    if (lane == k) myn = (unsigned)(mn & 0xffffffffu);
  }
  if (lane < NK) knn[(size_t)g * NK + lane] = (int)myn;
}

// ---------------- fused2: final (blocks 0-1023) + possub (1024-1215) ----------
// final self-gathers sample coords (same floats as posOut); possub blocks
// produce the posOut output. Independent -> safe in one launch.
constexpr int FINAL_BLKS = NB * NM / 16;            // 1024
constexpr int POSSUB_BLKS = (NB * 3 * NM + 255) / 256; // 192

__global__ __launch_bounds__(256) void fused2_kernel(const float* __restrict__ xT,
                                                     const float* __restrict__ pos,
                                                     const int* __restrict__ idx,
                                                     const unsigned* __restrict__ v1,
                                                     const int* __restrict__ knn,
                                                     float* __restrict__ xOut,
                                                     float* __restrict__ posOut) {
  __shared__ float tile[64][17];
  const int tid = threadIdx.x;
  if (blockIdx.x >= FINAL_BLKS) {
    // ---- possub: posOut[b,d,mm] = pos[b,d, compose(idx,v1)] ----
    int i = (blockIdx.x - FINAL_BLKS) * 256 + tid;
    if (i < NB * 3 * NM) {
      int mm = i & (NM - 1);
      int bd = i >> 11;            // b*3 + d
      int d = bd % 3, b = bd / 3;
      int raw = idx[b * NM + mm];
      int id = (mm < NFPS) ? raw : (int)v1[(size_t)b * NN + raw];
      posOut[i] = pos[((size_t)b * 3 + d) * NN + id];
    }
    return;
  }
  // ---- final: weights + gather + weighted sum ----
  const int wv = tid >> 6, lane = tid & 63;
  const int base = blockIdx.x * 16;      // 16 consecutive samples, same batch
  const int b = base >> 11;
  const float* pb = pos + (size_t)b * 3 * NN;
  for (int j = 0; j < 4; ++j) {
    const int ml = wv * 4 + j;           // 0..15
    const int g = base + ml;
    const int mm = g & (NM - 1);
    const int raw = idx[b * NM + mm];
    const int sid = (mm < NFPS) ? raw : (int)v1[(size_t)b * NN + raw];
    const float sx = pb[sid], sy = pb[NN + sid], sz = pb[2 * NN + sid];
    const int kk = lane & 15;
    const int nk = knn[(size_t)g * NK + kk];
    float dx = __fsub_rn(pb[nk], sx);
    float dy = __fsub_rn(pb[NN + nk], sy);
    float dz = __fsub_rn(pb[2 * NN + nk], sz);
    float dd = __fadd_rn(__fadd_rn(__fmul_rn(dx, dx), __fmul_rn(dy, dy)),
                         __fmul_rn(dz, dz));
    float d = __fsqrt_rn(dd);
    d = fmaxf(d, 1e-6f);
    float e = __fdiv_rn(0.0f - d, 0.2f);
    float mx = e;
#pragma unroll
    for (int off = 8; off > 0; off >>= 1) mx = fmaxf(mx, __shfl_xor(mx, off, 16));
    float ex = expf(__fsub_rn(e, mx));
    float sum = ex;
#pragma unroll
    for (int off = 8; off > 0; off >>= 1) sum = __fadd_rn(sum, __shfl_xor(sum, off, 16));
    float wgt = __fdiv_rn(ex, sum);
    float acc = 0.0f;
#pragma unroll
    for (int k = 0; k < NK; ++k) {
      float wk = __shfl(wgt, k, 64);
      int   nn = __shfl(nk, k, 64);
      acc = __fadd_rn(acc, __fmul_rn(wk, xT[((size_t)b * NN + nn) * NC + lane]));
    }
    tile[lane][ml] = acc;
  }
  __syncthreads();
  const int m0 = base & (NM - 1);
  for (int e2 = tid; e2 < 64 * 16; e2 += 256) {
    int c = e2 >> 4, ml = e2 & 15;
    xOut[((size_t)b * NC + c) * NM + m0 + ml] = tile[c][ml];
  }
}

extern "C" void kernel_launch(void* const* d_in, const int* in_sizes, int n_in,
                              void* d_out, int out_size, void* d_ws, size_t ws_size,
                              hipStream_t stream) {
  const float* x   = (const float*)d_in[0];
  const float* pos = (const float*)d_in[1];
  float* xOut   = (float*)d_out;
  float* posOut = xOut + (size_t)NB * NC * NM;

  char* w = (char*)d_ws;
  int*      idx    = (int*)(w + OFF_IDX);
  unsigned* v1     = (unsigned*)(w + OFF_V1);
  int*      knn    = (int*)(w + OFF_KNN);
  float*    xT     = (float*)(w + OFF_XT);

  hipLaunchKernelGGL(fused1_kernel, dim3(FPS_BLKS + PERM_BLKS + TR_BLKS), dim3(256), 0,
                     stream, pos, x, idx, v1, xT);
  hipLaunchKernelGGL(knn_kernel, dim3(NB * NM / 4), dim3(256), 0, stream, pos, idx, v1, knn);
  hipLaunchKernelGGL(fused2_kernel, dim3(FINAL_BLKS + POSSUB_BLKS), dim3(256), 0, stream,
                     xT, pos, idx, v1, knn, xOut, posOut);
}